// Round 1
// baseline (702.488 us; speedup 1.0000x reference)
//
#include <hip/hip_runtime.h>
#include <math.h>

#define BATCH 128
#define TLEN 512
#define XF 266
#define NF 96
#define HID 192
#define NC 250

// ---------------- K1: feature preparation ----------------

__device__ __forceinline__ void norm_hand(const float* __restrict__ xp, float* __restrict__ fp,
                                          int p0, int refp) {
  float rx = xp[2 * refp], ry = xp[2 * refp + 1];
  float px[21], py[21];
  float minx = 1e30f, maxx = -1e30f, miny = 1e30f, maxy = -1e30f;
#pragma unroll
  for (int i = 0; i < 21; ++i) {
    float ax = xp[2 * (p0 + i)] - rx;
    float ay = xp[2 * (p0 + i) + 1] - ry;
    px[i] = ax; py[i] = ay;
    minx = fminf(minx, ax); maxx = fmaxf(maxx, ax);
    miny = fminf(miny, ay); maxy = fmaxf(maxy, ay);
  }
  float s = fmaxf(maxx - minx, maxy - miny);
  if (s == 0.f) s = 1.f;
  float inv = 1.f / s;
#pragma unroll
  for (int i = 0; i < 21; ++i) {
    fp[2 * i] = px[i] * inv;
    fp[2 * i + 1] = py[i] * inv;
  }
}

__device__ __forceinline__ void norm_arm(const float* __restrict__ xp, float* __restrict__ fp,
                                         int a, int b, int c) {
  float rx = xp[0], ry = xp[1];  // ref = point 0 (center)
  float x0 = xp[2 * a] - rx, y0 = xp[2 * a + 1] - ry;
  float x1 = xp[2 * b] - rx, y1 = xp[2 * b + 1] - ry;
  float x2 = xp[2 * c] - rx, y2 = xp[2 * c + 1] - ry;
  float w = fmaxf(fmaxf(x0, x1), x2) - fminf(fminf(x0, x1), x2);
  float h = fmaxf(fmaxf(y0, y1), y2) - fminf(fminf(y0, y1), y2);
  float s = fmaxf(w, h);
  if (s == 0.f) s = 1.f;
  float inv = 1.f / s;
  fp[0] = x0 * inv; fp[1] = y0 * inv;
  fp[2] = x1 * inv; fp[3] = y1 * inv;
  fp[4] = x2 * inv; fp[5] = y2 * inv;
}

__global__ __launch_bounds__(256) void prep_kernel(const float* __restrict__ x,
                                                   float* __restrict__ feat) {
  int idx = blockIdx.x * 256 + threadIdx.x;
  if (idx >= BATCH * TLEN) return;
  const float* xp = x + (size_t)idx * XF;
  float* fp = feat + (size_t)idx * NF;
  norm_hand(xp, fp + 0, 112, 10);   // right hand: pts 112..132, ref pt 10
  norm_arm (xp, fp + 42, 6, 8, 10); // right arm: pts (6,8,10), ref center
  norm_hand(xp, fp + 48, 91, 9);    // left hand: pts 91..111, ref pt 9
  norm_arm (xp, fp + 90, 5, 7, 9);  // left arm: pts (5,7,9), ref center
}

// ---------------- K2: LSTM recurrence ----------------
// One block per (batch, lstm). Thread g owns gate row g; whh/wih rows in
// registers (templated, fully unrolled => no scratch spill). h in LDS
// (same-address broadcast reads, conflict-free). 2 barriers/step.

template <int H, int IN>
__device__ __forceinline__ void lstm_run(const float* __restrict__ fb,
                                         const float* __restrict__ wih,
                                         const float* __restrict__ whh,
                                         const float* __restrict__ bih,
                                         const float* __restrict__ bhh,
                                         float* __restrict__ cb,
                                         float* sh_h, float* sh_xf, float* sh_act,
                                         int tid) {
  constexpr int G = 4 * H;
  float wihr[IN];
  float whhr[H];
  float bias = 0.f;
  if (tid < G) {
#pragma unroll
    for (int j = 0; j < IN; ++j) wihr[j] = wih[tid * IN + j];
#pragma unroll
    for (int j = 0; j < H; ++j) whhr[j] = whh[tid * H + j];
    bias = bih[tid] + bhh[tid];
  }
  if (tid < H) sh_h[tid] = 0.f;
  float c = 0.f;
  __syncthreads();

  for (int t = 0; t < TLEN; ++t) {
    if (tid < IN) sh_xf[tid] = fb[t * NF + tid];
    __syncthreads();  // B1: xf staged, h (from prev step) visible
    float a = 0.f;
    if (tid < G) {
      float s = bias;
#pragma unroll
      for (int j = 0; j < IN; ++j) s += wihr[j] * sh_xf[j];
#pragma unroll
      for (int j = 0; j < H; ++j) s += whhr[j] * sh_h[j];
      if (tid / H == 2) a = tanhf(s);            // g gate
      else a = 1.f / (1.f + expf(-s));           // i, f, o gates
    }
    sh_act[tid] = a;
    __syncthreads();  // B2: activations visible; all reads of xf/h done
    if (tid < H) {
      float gi = sh_act[tid];
      float gf = sh_act[H + tid];
      float gg = sh_act[2 * H + tid];
      float go = sh_act[3 * H + tid];
      c = gf * c + gi * gg;
      float hn = go * tanhf(c);
      sh_h[tid] = hn;                          // read next iter after B1
      cb[(size_t)t * HID + tid] = hn;
    }
    // h/act write-read ordering for next iter is covered by next B1.
  }
}

__global__ __launch_bounds__(256) void lstm_kernel(
    const float* __restrict__ feat,
    const float* __restrict__ w0i, const float* __restrict__ w0h,
    const float* __restrict__ b0i, const float* __restrict__ b0h,
    const float* __restrict__ w1i, const float* __restrict__ w1h,
    const float* __restrict__ b1i, const float* __restrict__ b1h,
    const float* __restrict__ w2i, const float* __restrict__ w2h,
    const float* __restrict__ b2i, const float* __restrict__ b2h,
    const float* __restrict__ w3i, const float* __restrict__ w3h,
    const float* __restrict__ b3i, const float* __restrict__ b3h,
    float* __restrict__ combined) {
  __shared__ float sh_h[64];
  __shared__ float sh_xf[48];
  __shared__ float sh_act[256];
  int b = blockIdx.x;
  int l = blockIdx.y;
  int tid = threadIdx.x;
  const float* fb = feat + (size_t)b * TLEN * NF;
  float* cb = combined + (size_t)b * TLEN * HID;
  if (l == 0)      lstm_run<64, 42>(fb + 0,  w0i, w0h, b0i, b0h, cb + 0,   sh_h, sh_xf, sh_act, tid);
  else if (l == 1) lstm_run<32, 6>( fb + 42, w1i, w1h, b1i, b1h, cb + 64,  sh_h, sh_xf, sh_act, tid);
  else if (l == 2) lstm_run<64, 42>(fb + 48, w2i, w2h, b2i, b2h, cb + 96,  sh_h, sh_xf, sh_act, tid);
  else             lstm_run<32, 6>( fb + 90, w3i, w3h, b3i, b3h, cb + 160, sh_h, sh_xf, sh_act, tid);
}

// ---------------- K3: attention + FC ----------------
// One block per batch element.

__global__ __launch_bounds__(256) void attn_kernel(const float* __restrict__ combined,
                                                   const float* __restrict__ att_w,
                                                   const float* __restrict__ fc_w,
                                                   const float* __restrict__ fc_b,
                                                   float* __restrict__ dout) {
  __shared__ float sc[TLEN];
  __shared__ float aw[HID];
  __shared__ float ctx[HID];
  __shared__ float red[4];
  int b = blockIdx.x, tid = threadIdx.x;
  const float* cb = combined + (size_t)b * TLEN * HID;
  if (tid < HID) aw[tid] = att_w[tid];
  __syncthreads();

  float lmax = -1e30f;
  for (int t = tid; t < TLEN; t += 256) {
    const float* r = cb + (size_t)t * HID;
    float s = 0.f;
#pragma unroll 8
    for (int h = 0; h < HID; ++h) s += aw[h] * r[h];
    sc[t] = s;
    lmax = fmaxf(lmax, s);
  }
#pragma unroll
  for (int o = 32; o > 0; o >>= 1) lmax = fmaxf(lmax, __shfl_down(lmax, o, 64));
  if ((tid & 63) == 0) red[tid >> 6] = lmax;
  __syncthreads();
  float m = fmaxf(fmaxf(red[0], red[1]), fmaxf(red[2], red[3]));
  __syncthreads();

  float lsum = 0.f;
  for (int t = tid; t < TLEN; t += 256) {
    float e = expf(sc[t] - m);
    sc[t] = e;
    lsum += e;
  }
#pragma unroll
  for (int o = 32; o > 0; o >>= 1) lsum += __shfl_down(lsum, o, 64);
  if ((tid & 63) == 0) red[tid >> 6] = lsum;
  __syncthreads();
  float S = red[0] + red[1] + red[2] + red[3];
  float inv = 1.f / S;
  for (int t = tid; t < TLEN; t += 256) {
    float w = sc[t] * inv;
    sc[t] = w;
    dout[BATCH * NC + b * TLEN + t] = w;  // weights output (B,T,1)
  }
  __syncthreads();

  if (tid < HID) {
    float cx = 0.f;
#pragma unroll 8
    for (int t = 0; t < TLEN; ++t) cx += sc[t] * cb[(size_t)t * HID + tid];
    ctx[tid] = cx;
  }
  __syncthreads();

  if (tid < NC) {
    const float* wr = fc_w + (size_t)tid * HID;
    float s = fc_b[tid];
#pragma unroll 8
    for (int h = 0; h < HID; ++h) s += ctx[h] * wr[h];
    dout[b * NC + tid] = s;  // logits output (B,250)
  }
}

// ---------------- launcher ----------------

extern "C" void kernel_launch(void* const* d_in, const int* in_sizes, int n_in,
                              void* d_out, int out_size, void* d_ws, size_t ws_size,
                              hipStream_t stream) {
  const float* x = (const float*)d_in[0];
  const float* wih_rh = (const float*)d_in[1];
  const float* whh_rh = (const float*)d_in[2];
  const float* bih_rh = (const float*)d_in[3];
  const float* bhh_rh = (const float*)d_in[4];
  const float* wih_ra = (const float*)d_in[5];
  const float* whh_ra = (const float*)d_in[6];
  const float* bih_ra = (const float*)d_in[7];
  const float* bhh_ra = (const float*)d_in[8];
  const float* wih_lh = (const float*)d_in[9];
  const float* whh_lh = (const float*)d_in[10];
  const float* bih_lh = (const float*)d_in[11];
  const float* bhh_lh = (const float*)d_in[12];
  const float* wih_la = (const float*)d_in[13];
  const float* whh_la = (const float*)d_in[14];
  const float* bih_la = (const float*)d_in[15];
  const float* bhh_la = (const float*)d_in[16];
  const float* att_w = (const float*)d_in[17];
  const float* fc_w = (const float*)d_in[18];
  const float* fc_b = (const float*)d_in[19];

  float* feat = (float*)d_ws;                         // 128*512*96 floats = 25.2 MB
  float* combined = feat + (size_t)BATCH * TLEN * NF; // 128*512*192 floats = 50.3 MB

  prep_kernel<<<dim3((BATCH * TLEN + 255) / 256), 256, 0, stream>>>(x, feat);
  lstm_kernel<<<dim3(BATCH, 4), 256, 0, stream>>>(
      feat,
      wih_rh, whh_rh, bih_rh, bhh_rh,
      wih_ra, whh_ra, bih_ra, bhh_ra,
      wih_lh, whh_lh, bih_lh, bhh_lh,
      wih_la, whh_la, bih_la, bhh_la,
      combined);
  attn_kernel<<<dim3(BATCH), 256, 0, stream>>>(combined, att_w, fc_w, fc_b, (float*)d_out);
}